// Round 7
// baseline (96679.541 us; speedup 1.0000x reference)
//
#include <hip/hip_runtime.h>

#define B_ 32
#define T_FULL 4096
#define EMB_ 256
#define XD_ 768
#define H_ 896
#define G3_ 2688
#define O_ 512
#define NWG_SCAN 28
#define THR_SCAN 768

typedef __attribute__((ext_vector_type(8))) short bf16x8;
typedef __attribute__((ext_vector_type(4))) float f32x4;
typedef __attribute__((ext_vector_type(16))) float f32x16;

__device__ __forceinline__ f32x4 mfma16(bf16x8 a, bf16x8 b, f32x4 c) {
  return __builtin_amdgcn_mfma_f32_16x16x32_bf16(a, b, c, 0, 0, 0);
}
__device__ __forceinline__ f32x16 mfma32(bf16x8 a, bf16x8 b, f32x16 c) {
  return __builtin_amdgcn_mfma_f32_32x32x16_bf16(a, b, c, 0, 0, 0);
}

__device__ __forceinline__ unsigned short f2bf(float x) {
  union { float f; unsigned u; } v; v.f = x;
  unsigned r = v.u + 0x7fffu + ((v.u >> 16) & 1u);
  return (unsigned short)(r >> 16);
}
__device__ __forceinline__ float bf2f(unsigned short h) {
  union { float f; unsigned u; } v; v.u = ((unsigned)h) << 16;
  return v.f;
}

__device__ __forceinline__ unsigned aload32(const unsigned* p) {
  return __hip_atomic_load((unsigned*)p, __ATOMIC_RELAXED, __HIP_MEMORY_SCOPE_AGENT);
}
__device__ __forceinline__ void astore32(unsigned* p, unsigned v) {
  __hip_atomic_store(p, v, __ATOMIC_RELAXED, __HIP_MEMORY_SCOPE_AGENT);
}

// swizzled h layout: row = batch (0..31), 1792 B/row; granule (16B) index g of byte
// col cb: g' = (g & ~15) | ((g & 15) ^ (row & 15)); planes hi/lo offset 57344.
__device__ __forceinline__ int hswz(int row, int cb) {
  const int g = cb >> 4;
  const int gs = (g & ~15) | ((g & 15) ^ (row & 15));
  return row * 1792 + (gs << 4) + (cb & 15);
}

__global__ __launch_bounds__(256) void cvt_bf16(const float* __restrict__ in,
                                                unsigned short* __restrict__ out, int n) {
  for (int i = blockIdx.x * 256 + threadIdx.x; i < n; i += gridDim.x * 256)
    out[i] = f2bf(in[i]);
}

// VAR: 0 = gates (A = concat(emb[sample], icnd) built on the fly, out fp32 [row][2688])
//      1 = fc1   (A = ornn bf16, out bf16 relu [row][896])
//      2 = fc2   (A = hidden bf16, out fp32 scattered to d_out [b][t][512])
template<int VAR>
__global__ __launch_bounds__(256) void gemm_bf16(
    const unsigned short* __restrict__ A,
    const int* __restrict__ sample,
    const float* __restrict__ icnd,
    const unsigned short* __restrict__ embb,
    const unsigned short* __restrict__ W,
    const float* __restrict__ bias,
    float* __restrict__ outf,
    unsigned short* __restrict__ outb,
    int t0) {
  constexpr int K = (VAR == 0) ? XD_ : H_;
  constexpr int N = (VAR == 0) ? G3_ : (VAR == 1 ? H_ : O_);
  constexpr int LDT = 48;
  __shared__ __align__(16) unsigned short Asl[128 * LDT];
  __shared__ __align__(16) unsigned short Bsl[128 * LDT];
  const int tid = threadIdx.x;
  const int rowBase = blockIdx.y * 128, colBase = blockIdx.x * 128;
  const int lane = tid & 63, wid = tid >> 6;
  const int wm = wid >> 1, wn = wid & 1;
  const int lr = lane & 15, lk = lane >> 4;
  const f32x4 fzero = {0.f, 0.f, 0.f, 0.f};
  f32x4 acc[4][4];
#pragma unroll
  for (int i = 0; i < 4; ++i)
#pragma unroll
    for (int j = 0; j < 4; ++j) acc[i][j] = fzero;

  for (int k0 = 0; k0 < K; k0 += 32) {
#pragma unroll
    for (int s = 0; s < 2; ++s) {
      const int seg = tid + s * 256;           // 512 segments of 8 elems
      const int r = seg >> 2, kg = (seg & 3) * 8;
      const int kk = k0 + kg;
      bf16x8 va;
      if (VAR == 0) {
        const int rowG = rowBase + r;
        const int b = rowG & 31, t = t0 + (rowG >> 5);
        if (kk < EMB_) {
          const int e = sample[b * T_FULL + t];
          va = *(const bf16x8*)(embb + e * EMB_ + kk);
        } else {
          const float* p = icnd + ((size_t)(b * T_FULL + t)) * 512 + (kk - EMB_);
          const float4 f0 = *(const float4*)p;
          const float4 f1 = *(const float4*)(p + 4);
          va[0] = (short)f2bf(f0.x); va[1] = (short)f2bf(f0.y);
          va[2] = (short)f2bf(f0.z); va[3] = (short)f2bf(f0.w);
          va[4] = (short)f2bf(f1.x); va[5] = (short)f2bf(f1.y);
          va[6] = (short)f2bf(f1.z); va[7] = (short)f2bf(f1.w);
        }
      } else {
        va = *(const bf16x8*)(A + (size_t)(rowBase + r) * K + kk);
      }
      *(bf16x8*)(Asl + r * LDT + kg) = va;
      *(bf16x8*)(Bsl + r * LDT + kg) = *(const bf16x8*)(W + (size_t)(colBase + r) * K + kk);
    }
    __syncthreads();
    bf16x8 af[4], bfr[4];
#pragma unroll
    for (int mt = 0; mt < 4; ++mt)
      af[mt] = *(const bf16x8*)(Asl + (wm * 64 + mt * 16 + lr) * LDT + lk * 8);
#pragma unroll
    for (int nt = 0; nt < 4; ++nt)
      bfr[nt] = *(const bf16x8*)(Bsl + (wn * 64 + nt * 16 + lr) * LDT + lk * 8);
#pragma unroll
    for (int mt = 0; mt < 4; ++mt)
#pragma unroll
      for (int nt = 0; nt < 4; ++nt) acc[mt][nt] = mfma16(af[mt], bfr[nt], acc[mt][nt]);
    __syncthreads();
  }

#pragma unroll
  for (int mt = 0; mt < 4; ++mt) {
#pragma unroll
    for (int nt = 0; nt < 4; ++nt) {
      const int colG = colBase + wn * 64 + nt * 16 + lr;
      const float bv = bias[colG];
#pragma unroll
      for (int r = 0; r < 4; ++r) {
        const int rowG = rowBase + wm * 64 + mt * 16 + lk * 4 + r;
        const float v = acc[mt][nt][r] + bv;
        if (VAR == 0) {
          outf[(size_t)rowG * N + colG] = v;
        } else if (VAR == 1) {
          outb[(size_t)rowG * N + colG] = f2bf(fmaxf(v, 0.f));
        } else {
          const int b = rowG & 31, t = t0 + (rowG >> 5);
          outf[((size_t)(b * T_FULL + t)) * O_ + colG] = v;
        }
      }
    }
  }
}

// Persistent GRU scan v7. 28 WGs x 768 threads (12 waves = 3 strips x 4 K-quarters).
// Register-free data movement:
//  P1: h gather = async global_load_lds (16B, aux=SC0|SC1 bypass) identity-copy of the
//      pre-swizzled global h layout -> zero VGPR staging, ONE latency exposure.
//  P2: 32x32x16 MFMA; weights streamed in-loop from L1/L2 (plain b128, pipelined by
//      compiler as in v3); h from swizzled LDS. Partials merged via LDS atomicAdd.
//  P3: elementwise GRU cell; h stores via agent-scope atomics (write to coherence pt).
//  P4: drain, arrival slot store, wave0 lane-parallel poll (fence-free barrier).
__global__ __launch_bounds__(THR_SCAN, 3) void scan_gru(
    const float* __restrict__ gates,          // [Tc*32][2688] fp32
    const unsigned short* __restrict__ whh,   // [2688][896] bf16
    const float* __restrict__ bhh,            // [2688]
    unsigned long long* __restrict__ hbuf,    // [2][114688 B] swizzled h (hi|lo planes)
    unsigned short* __restrict__ ornn,        // [Tc*32][896] bf16
    unsigned int* __restrict__ arr,           // arrival slots (zeroed per call)
    int t0, int Tc) {
  __shared__ __align__(16) char hst[114688];  // identical layout to hbuf plane
  __shared__ float gh2f[2 * 96 * 32];         // 24576 B partial sums
  const int tid = threadIdx.x;
  const int j0 = blockIdx.x * 32;
  const int lane = tid & 63, wid = tid >> 6;
  const int l31 = lane & 31, lhi = lane >> 5;
  const int s = wid >> 2, kq = wid & 3;       // strip / K-quarter
  const int ph = kq >> 1;                     // partial slot
  const int eb = tid >> 4, ec = (tid & 15) * 2;  // elementwise identity (tid<512)

  // weight base pointer for this wave's (s, kq) slice (streamed per step)
  const unsigned short* wp = whh + (size_t)(s * H_ + j0 + l31) * H_ + kq * 224 + lhi * 8;

  // ---- persistent: bias + fp32 h state for own 2 units ----
  float bh0 = 0.f, bh1 = 0.f, bh2 = 0.f, bh3 = 0.f, bh4 = 0.f, bh5 = 0.f;
  float hown0 = 0.f, hown1 = 0.f;
  if (tid < 512) {
    const int j = j0 + ec;
    bh0 = bhh[j];          bh1 = bhh[j + 1];
    bh2 = bhh[H_ + j];     bh3 = bhh[H_ + j + 1];
    bh4 = bhh[2 * H_ + j]; bh5 = bhh[2 * H_ + j + 1];
    const int rb0 = (t0 + 1) & 1;
    const char* hb = (const char*)hbuf + rb0 * 114688;
    const int off = hswz(eb, 2 * j);
    const unsigned hi01 = aload32((const unsigned*)(hb + off));
    const unsigned lo01 = aload32((const unsigned*)(hb + off + 57344));
    hown0 = bf2f((unsigned short)(hi01 & 0xffff)) + bf2f((unsigned short)(lo01 & 0xffff));
    hown1 = bf2f((unsigned short)(hi01 >> 16)) + bf2f((unsigned short)(lo01 >> 16));
  }

  for (int tl = 0; tl < Tc; ++tl) {
    const int t = t0 + tl;
    const int rb = (t + 1) & 1, wb = t & 1;

    // ---- P1: zero gh2, gates prefetch, async register-free gather ----
    {
      const f32x4 z4 = {0.f, 0.f, 0.f, 0.f};
      *(f32x4*)(gh2f + tid * 8) = z4;
      *(f32x4*)(gh2f + tid * 8 + 4) = z4;
    }
    float2 pxr = {0.f, 0.f}, pxz = {0.f, 0.f}, pxn = {0.f, 0.f};
    if (tid < 512) {
      const float* gx = gates + ((size_t)tl * 32 + eb) * G3_;
      pxr = *(const float2*)(gx + j0 + ec);
      pxz = *(const float2*)(gx + H_ + j0 + ec);
      pxn = *(const float2*)(gx + 2 * H_ + j0 + ec);
    }
    {
      const char* gsrc = (const char*)hbuf + (size_t)rb * 114688;
      // 112 x 1KB wave-transactions; wave w issues q = w, w+12, ... (9-10 each)
#pragma unroll
      for (int j = 0; j < 10; ++j) {
        const int q = wid + 12 * j;
        if (q < 112) {
          const __attribute__((address_space(1))) unsigned* g =
              (const __attribute__((address_space(1))) unsigned*)(gsrc + q * 1024 + (lane << 4));
          __builtin_amdgcn_global_load_lds(
              g, (__attribute__((address_space(3))) unsigned*)(hst + q * 1024),
              16, 0, 0x11 /* SC0|SC1: read at coherence point */);
        }
      }
    }
    asm volatile("s_waitcnt vmcnt(0)" ::: "memory");
    __syncthreads();

    // ---- P2: 32x32x16 MFMA, weights streamed from L2, h from swizzled LDS ----
    {
      f32x16 acc;
#pragma unroll
      for (int r = 0; r < 16; ++r) acc[r] = 0.f;
#pragma unroll
      for (int i = 0; i < 14; ++i) {
        const int g = (kq * 14 + i) * 2 + lhi;
        const int gs = (g & ~15) | ((g & 15) ^ (l31 & 15));
        const int off = l31 * 1792 + (gs << 4);
        const bf16x8 bh = *(const bf16x8*)(hst + off);
        const bf16x8 bl = *(const bf16x8*)(hst + 57344 + off);
        const bf16x8 bw = *(const bf16x8*)(wp + i * 16);
        acc = mfma32(bw, bh, acc);
        acc = mfma32(bw, bl, acc);
      }
#pragma unroll
      for (int r = 0; r < 16; ++r) {
        const int rowD = (r & 3) + 8 * (r >> 2) + 4 * lhi;
        atomicAdd(&gh2f[(ph * 96 + s * 32 + rowD) * 32 + (l31 ^ rowD)], acc[r]);
      }
    }
    __syncthreads();

    // ---- P3: elementwise GRU cell + swizzled h stores + ornn ----
    if (tid < 512) {
      const int b0 = (0 * 32 + ec) * 32, b1 = (1 * 32 + ec) * 32, b2 = (2 * 32 + ec) * 32;
      const int c0 = eb ^ ec, c1 = eb ^ (ec + 1);
      const float ghr0 = gh2f[b0 + c0] + gh2f[3072 + b0 + c0] + bh0;
      const float ghr1 = gh2f[b0 + 32 + c1] + gh2f[3072 + b0 + 32 + c1] + bh1;
      const float ghz0 = gh2f[b1 + c0] + gh2f[3072 + b1 + c0] + bh2;
      const float ghz1 = gh2f[b1 + 32 + c1] + gh2f[3072 + b1 + 32 + c1] + bh3;
      const float ghn0 = gh2f[b2 + c0] + gh2f[3072 + b2 + c0] + bh4;
      const float ghn1 = gh2f[b2 + 32 + c1] + gh2f[3072 + b2 + 32 + c1] + bh5;
      const float r0 = 1.f / (1.f + __expf(-(pxr.x + ghr0)));
      const float r1 = 1.f / (1.f + __expf(-(pxr.y + ghr1)));
      const float z0 = 1.f / (1.f + __expf(-(pxz.x + ghz0)));
      const float z1 = 1.f / (1.f + __expf(-(pxz.y + ghz1)));
      const float e0 = __expf(2.f * (pxn.x + r0 * ghn0));
      const float e1 = __expf(2.f * (pxn.y + r1 * ghn1));
      const float n0 = 1.f - 2.f / (e0 + 1.f);
      const float n1 = 1.f - 2.f / (e1 + 1.f);
      hown0 = (1.f - z0) * n0 + z0 * hown0;
      hown1 = (1.f - z1) * n1 + z1 * hown1;
      const unsigned short h0 = f2bf(hown0), h1 = f2bf(hown1);
      const unsigned short l0 = f2bf(hown0 - bf2f(h0)), l1 = f2bf(hown1 - bf2f(h1));
      const unsigned hi01 = (unsigned)h0 | ((unsigned)h1 << 16);
      const unsigned lo01 = (unsigned)l0 | ((unsigned)l1 << 16);
      char* hb = (char*)hbuf + wb * 114688;
      const int off = hswz(eb, 2 * (j0 + ec));
      astore32((unsigned*)(hb + off), hi01);
      astore32((unsigned*)(hb + off + 57344), lo01);
      *(unsigned*)(ornn + ((size_t)tl * 32 + eb) * H_ + j0 + ec) = hi01;
    }

    // ---- P4: drain, arrive, lane-parallel poll ----
    asm volatile("s_waitcnt vmcnt(0)" ::: "memory");
    __syncthreads();
    const unsigned tgt = (unsigned)(t + 1);
    if (tid == 0) astore32(arr + blockIdx.x, tgt);
    if (wid == 0) {
      for (;;) {
        const unsigned v = (lane < NWG_SCAN) ? aload32(arr + lane) : tgt;
        if (__all(v >= tgt)) break;
        __builtin_amdgcn_s_sleep(1);
      }
    }
    __syncthreads();
  }
}

extern "C" void kernel_launch(void* const* d_in, const int* in_sizes, int n_in,
                              void* d_out, int out_size, void* d_ws, size_t ws_size,
                              hipStream_t stream) {
  (void)in_sizes; (void)n_in; (void)out_size;
  const int* sample = (const int*)d_in[0];
  const float* icnd = (const float*)d_in[1];
  const float* emb = (const float*)d_in[2];
  const float* wih = (const float*)d_in[3];
  const float* whh = (const float*)d_in[4];
  const float* bih = (const float*)d_in[5];
  const float* bhh = (const float*)d_in[6];
  const float* fc1w = (const float*)d_in[7];
  const float* fc1b = (const float*)d_in[8];
  const float* fc2w = (const float*)d_in[9];
  const float* fc2b = (const float*)d_in[10];
  float* out = (float*)d_out;
  char* ws = (char*)d_ws;

  size_t off = 0;
  auto alloc = [&](size_t bytes) {
    size_t o = off;
    off = (off + bytes + 255) & ~(size_t)255;
    return o;
  };
  const size_t o_arr = alloc(256);
  const size_t o_h = alloc((size_t)2 * 114688);  // swizzled h, 2 time slots
  const size_t zero_end = off;
  const size_t o_emb = alloc((size_t)O_ * EMB_ * 2);
  const size_t o_wih = alloc((size_t)G3_ * XD_ * 2);
  const size_t o_whh = alloc((size_t)G3_ * H_ * 2);
  const size_t o_f1w = alloc((size_t)H_ * H_ * 2);
  const size_t o_f2w = alloc((size_t)O_ * H_ * 2);
  const size_t head = off;

  int Tc = 512;
  while (Tc > 8) {
    size_t need = head + (size_t)Tc * 32 * G3_ * 4 + 2 * ((size_t)Tc * 32 * H_ * 2) + 4096;
    if (need <= ws_size) break;
    Tc >>= 1;
  }
  const size_t o_gat = alloc((size_t)Tc * 32 * G3_ * 4);
  const size_t o_orn = alloc((size_t)Tc * 32 * H_ * 2);
  const size_t o_hid = alloc((size_t)Tc * 32 * H_ * 2);
  (void)o_gat; (void)o_orn; (void)o_hid;

  unsigned short* embb = (unsigned short*)(ws + o_emb);
  unsigned short* wihb = (unsigned short*)(ws + o_wih);
  unsigned short* whhb = (unsigned short*)(ws + o_whh);
  unsigned short* f1wb = (unsigned short*)(ws + o_f1w);
  unsigned short* f2wb = (unsigned short*)(ws + o_f2w);
  float* gat = (float*)(ws + o_gat);
  unsigned short* orn = (unsigned short*)(ws + o_orn);
  unsigned short* hid = (unsigned short*)(ws + o_hid);
  unsigned long long* hbuf = (unsigned long long*)(ws + o_h);
  unsigned int* arr = (unsigned int*)(ws + o_arr);

  // zero arrival slots + h state (required every call: deterministic replays)
  (void)hipMemsetAsync(ws, 0, zero_end, stream);

  cvt_bf16<<<512, 256, 0, stream>>>(emb, embb, O_ * EMB_);
  cvt_bf16<<<1024, 256, 0, stream>>>(wih, wihb, G3_ * XD_);
  cvt_bf16<<<1024, 256, 0, stream>>>(whh, whhb, G3_ * H_);
  cvt_bf16<<<512, 256, 0, stream>>>(fc1w, f1wb, H_ * H_);
  cvt_bf16<<<512, 256, 0, stream>>>(fc2w, f2wb, O_ * H_);

  const int nch = T_FULL / Tc;
  const int M = Tc * 32;
  for (int c = 0; c < nch; ++c) {
    const int t0 = c * Tc;
    gemm_bf16<0><<<dim3(G3_ / 128, M / 128), 256, 0, stream>>>(
        nullptr, sample, icnd, embb, wihb, bih, gat, nullptr, t0);
    scan_gru<<<NWG_SCAN, THR_SCAN, 0, stream>>>(gat, whhb, bhh, hbuf, orn, arr, t0, Tc);
    gemm_bf16<1><<<dim3(H_ / 128, M / 128), 256, 0, stream>>>(
        orn, nullptr, nullptr, nullptr, f1wb, fc1b, nullptr, hid, t0);
    gemm_bf16<2><<<dim3(O_ / 128, M / 128), 256, 0, stream>>>(
        hid, nullptr, nullptr, nullptr, f2wb, fc2b, out, nullptr, t0);
  }
}

// Round 8
// 39668.066 us; speedup vs baseline: 2.4372x; 2.4372x over previous
//
#include <hip/hip_runtime.h>

#define B_ 32
#define T_FULL 4096
#define EMB_ 256
#define XD_ 768
#define H_ 896
#define G3_ 2688
#define O_ 512
#define NWG_SCAN 28
#define THR_SCAN 768

typedef __attribute__((ext_vector_type(8))) short bf16x8;
typedef __attribute__((ext_vector_type(4))) float f32x4;
typedef __attribute__((ext_vector_type(16))) float f32x16;

__device__ __forceinline__ f32x4 mfma16(bf16x8 a, bf16x8 b, f32x4 c) {
  return __builtin_amdgcn_mfma_f32_16x16x32_bf16(a, b, c, 0, 0, 0);
}
__device__ __forceinline__ f32x16 mfma32(bf16x8 a, bf16x8 b, f32x16 c) {
  return __builtin_amdgcn_mfma_f32_32x32x16_bf16(a, b, c, 0, 0, 0);
}

__device__ __forceinline__ unsigned short f2bf(float x) {
  union { float f; unsigned u; } v; v.f = x;
  unsigned r = v.u + 0x7fffu + ((v.u >> 16) & 1u);
  return (unsigned short)(r >> 16);
}
__device__ __forceinline__ float bf2f(unsigned short h) {
  union { float f; unsigned u; } v; v.u = ((unsigned)h) << 16;
  return v.f;
}

__device__ __forceinline__ unsigned long long aload64(const unsigned long long* p) {
  return __hip_atomic_load((unsigned long long*)p, __ATOMIC_RELAXED, __HIP_MEMORY_SCOPE_AGENT);
}
__device__ __forceinline__ unsigned aload32(const unsigned* p) {
  return __hip_atomic_load((unsigned*)p, __ATOMIC_RELAXED, __HIP_MEMORY_SCOPE_AGENT);
}
__device__ __forceinline__ void astore32(unsigned* p, unsigned v) {
  __hip_atomic_store(p, v, __ATOMIC_RELAXED, __HIP_MEMORY_SCOPE_AGENT);
}

// swizzled h layout: row = batch (0..31), 1792 B/row; granule (16B) index g of byte
// col cb: g' = (g & ~15) | ((g & 15) ^ (row & 15)); planes hi/lo offset 57344.
__device__ __forceinline__ int hswz(int row, int cb) {
  const int g = cb >> 4;
  const int gs = (g & ~15) | ((g & 15) ^ (row & 15));
  return row * 1792 + (gs << 4) + (cb & 15);
}

__global__ __launch_bounds__(256) void cvt_bf16(const float* __restrict__ in,
                                                unsigned short* __restrict__ out, int n) {
  for (int i = blockIdx.x * 256 + threadIdx.x; i < n; i += gridDim.x * 256)
    out[i] = f2bf(in[i]);
}

// VAR: 0 = gates (A = concat(emb[sample], icnd) built on the fly, out fp32 [row][2688])
//      1 = fc1   (A = ornn bf16, out bf16 relu [row][896])
//      2 = fc2   (A = hidden bf16, out fp32 scattered to d_out [b][t][512])
template<int VAR>
__global__ __launch_bounds__(256) void gemm_bf16(
    const unsigned short* __restrict__ A,
    const int* __restrict__ sample,
    const float* __restrict__ icnd,
    const unsigned short* __restrict__ embb,
    const unsigned short* __restrict__ W,
    const float* __restrict__ bias,
    float* __restrict__ outf,
    unsigned short* __restrict__ outb,
    int t0) {
  constexpr int K = (VAR == 0) ? XD_ : H_;
  constexpr int N = (VAR == 0) ? G3_ : (VAR == 1 ? H_ : O_);
  constexpr int LDT = 48;
  __shared__ __align__(16) unsigned short Asl[128 * LDT];
  __shared__ __align__(16) unsigned short Bsl[128 * LDT];
  const int tid = threadIdx.x;
  const int rowBase = blockIdx.y * 128, colBase = blockIdx.x * 128;
  const int lane = tid & 63, wid = tid >> 6;
  const int wm = wid >> 1, wn = wid & 1;
  const int lr = lane & 15, lk = lane >> 4;
  const f32x4 fzero = {0.f, 0.f, 0.f, 0.f};
  f32x4 acc[4][4];
#pragma unroll
  for (int i = 0; i < 4; ++i)
#pragma unroll
    for (int j = 0; j < 4; ++j) acc[i][j] = fzero;

  for (int k0 = 0; k0 < K; k0 += 32) {
#pragma unroll
    for (int s = 0; s < 2; ++s) {
      const int seg = tid + s * 256;           // 512 segments of 8 elems
      const int r = seg >> 2, kg = (seg & 3) * 8;
      const int kk = k0 + kg;
      bf16x8 va;
      if (VAR == 0) {
        const int rowG = rowBase + r;
        const int b = rowG & 31, t = t0 + (rowG >> 5);
        if (kk < EMB_) {
          const int e = sample[b * T_FULL + t];
          va = *(const bf16x8*)(embb + e * EMB_ + kk);
        } else {
          const float* p = icnd + ((size_t)(b * T_FULL + t)) * 512 + (kk - EMB_);
          const float4 f0 = *(const float4*)p;
          const float4 f1 = *(const float4*)(p + 4);
          va[0] = (short)f2bf(f0.x); va[1] = (short)f2bf(f0.y);
          va[2] = (short)f2bf(f0.z); va[3] = (short)f2bf(f0.w);
          va[4] = (short)f2bf(f1.x); va[5] = (short)f2bf(f1.y);
          va[6] = (short)f2bf(f1.z); va[7] = (short)f2bf(f1.w);
        }
      } else {
        va = *(const bf16x8*)(A + (size_t)(rowBase + r) * K + kk);
      }
      *(bf16x8*)(Asl + r * LDT + kg) = va;
      *(bf16x8*)(Bsl + r * LDT + kg) = *(const bf16x8*)(W + (size_t)(colBase + r) * K + kk);
    }
    __syncthreads();
    bf16x8 af[4], bfr[4];
#pragma unroll
    for (int mt = 0; mt < 4; ++mt)
      af[mt] = *(const bf16x8*)(Asl + (wm * 64 + mt * 16 + lr) * LDT + lk * 8);
#pragma unroll
    for (int nt = 0; nt < 4; ++nt)
      bfr[nt] = *(const bf16x8*)(Bsl + (wn * 64 + nt * 16 + lr) * LDT + lk * 8);
#pragma unroll
    for (int mt = 0; mt < 4; ++mt)
#pragma unroll
      for (int nt = 0; nt < 4; ++nt) acc[mt][nt] = mfma16(af[mt], bfr[nt], acc[mt][nt]);
    __syncthreads();
  }

#pragma unroll
  for (int mt = 0; mt < 4; ++mt) {
#pragma unroll
    for (int nt = 0; nt < 4; ++nt) {
      const int colG = colBase + wn * 64 + nt * 16 + lr;
      const float bv = bias[colG];
#pragma unroll
      for (int r = 0; r < 4; ++r) {
        const int rowG = rowBase + wm * 64 + mt * 16 + lk * 4 + r;
        const float v = acc[mt][nt][r] + bv;
        if (VAR == 0) {
          outf[(size_t)rowG * N + colG] = v;
        } else if (VAR == 1) {
          outb[(size_t)rowG * N + colG] = f2bf(fmaxf(v, 0.f));
        } else {
          const int b = rowG & 31, t = t0 + (rowG >> 5);
          outf[((size_t)(b * T_FULL + t)) * O_ + colG] = v;
        }
      }
    }
  }
}

// Persistent GRU scan v8. 28 WGs x 768 threads.
// P1: gates prefetch + identity-copy gather (two register batches, 10+9 u64).
// P2: 6 MFMA waves = 3 strips x 2 K-halves, mfma32; weights streamed from L2;
//     gh partials in DISJOINT slots via plain ds stores (no atomics anywhere).
// P3: elementwise GRU cell (512 threads), merging the 2 K-half slots; agent-scope
//     h stores to the pre-swizzled global layout.
// P4: drain, arrival slot, wave0 lane-parallel poll (fence-free barrier).
__global__ __launch_bounds__(THR_SCAN, 3) void scan_gru(
    const float* __restrict__ gates,          // [Tc*32][2688] fp32
    const unsigned short* __restrict__ whh,   // [2688][896] bf16
    const float* __restrict__ bhh,            // [2688]
    unsigned long long* __restrict__ hbuf,    // [2][114688 B] swizzled h (hi|lo planes)
    unsigned short* __restrict__ ornn,        // [Tc*32][896] bf16
    unsigned int* __restrict__ arr,           // arrival slots (zeroed per call)
    int t0, int Tc) {
  __shared__ __align__(16) char hst[114688];  // identical layout to hbuf plane
  __shared__ float gh2f[2 * 96 * 32];         // [kh][96 rows][32 cols] partials
  const int tid = threadIdx.x;
  const int j0 = blockIdx.x * 32;
  const int lane = tid & 63, wid = tid >> 6;
  const int l31 = lane & 31, lhi = lane >> 5;
  const int eb = tid >> 4, ec = (tid & 15) * 2;  // elementwise identity (tid<512)

  // ---- persistent: bias + fp32 h state for own 2 units ----
  float bh0 = 0.f, bh1 = 0.f, bh2 = 0.f, bh3 = 0.f, bh4 = 0.f, bh5 = 0.f;
  float hown0 = 0.f, hown1 = 0.f;
  if (tid < 512) {
    const int j = j0 + ec;
    bh0 = bhh[j];          bh1 = bhh[j + 1];
    bh2 = bhh[H_ + j];     bh3 = bhh[H_ + j + 1];
    bh4 = bhh[2 * H_ + j]; bh5 = bhh[2 * H_ + j + 1];
    const int rb0 = (t0 + 1) & 1;
    const char* hb = (const char*)hbuf + rb0 * 114688;
    const int off = hswz(eb, 2 * j);
    const unsigned hi01 = aload32((const unsigned*)(hb + off));
    const unsigned lo01 = aload32((const unsigned*)(hb + off + 57344));
    hown0 = bf2f((unsigned short)(hi01 & 0xffff)) + bf2f((unsigned short)(lo01 & 0xffff));
    hown1 = bf2f((unsigned short)(hi01 >> 16)) + bf2f((unsigned short)(lo01 >> 16));
  }

  for (int tl = 0; tl < Tc; ++tl) {
    const int t = t0 + tl;
    const int rb = (t + 1) & 1, wb = t & 1;

    // ---- P1: gates prefetch + identity-copy register-batched gather ----
    float2 pxr = {0.f, 0.f}, pxz = {0.f, 0.f}, pxn = {0.f, 0.f};
    if (tid < 512) {
      const float* gx = gates + ((size_t)tl * 32 + eb) * G3_;
      pxr = *(const float2*)(gx + j0 + ec);
      pxz = *(const float2*)(gx + H_ + j0 + ec);
      pxn = *(const float2*)(gx + 2 * H_ + j0 + ec);
    }
    {
      const unsigned long long* src = hbuf + (size_t)rb * 14336;
      unsigned long long rg[10];
#pragma unroll
      for (int k = 0; k < 10; ++k) rg[k] = aload64(src + tid + k * 768);
      __builtin_amdgcn_sched_barrier(0);
#pragma unroll
      for (int k = 0; k < 10; ++k)
        *(unsigned long long*)(hst + (size_t)(tid + k * 768) * 8) = rg[k];
      unsigned long long rg2[9];
#pragma unroll
      for (int k = 0; k < 9; ++k) {
        const int i = tid + (10 + k) * 768;
        rg2[k] = (i < 14336) ? aload64(src + i) : 0ull;
      }
      __builtin_amdgcn_sched_barrier(0);
#pragma unroll
      for (int k = 0; k < 9; ++k) {
        const int i = tid + (10 + k) * 768;
        if (i < 14336) *(unsigned long long*)(hst + (size_t)i * 8) = rg2[k];
      }
    }
    __syncthreads();

    // ---- P2: 6 waves (3 strips x 2 K-halves), mfma32, disjoint plain stores ----
    if (wid < 6) {
      const int s2 = wid >> 1, kh = wid & 1;
      const unsigned short* wp =
          whh + (size_t)(s2 * H_ + j0 + l31) * H_ + kh * 448 + lhi * 8;
      f32x16 acc;
#pragma unroll
      for (int r = 0; r < 16; ++r) acc[r] = 0.f;
#pragma unroll
      for (int i = 0; i < 28; ++i) {
        const int g = (kh * 28 + i) * 2 + lhi;
        const int gs = (g & ~15) | ((g & 15) ^ (l31 & 15));
        const int off = l31 * 1792 + (gs << 4);
        const bf16x8 bh = *(const bf16x8*)(hst + off);
        const bf16x8 bl = *(const bf16x8*)(hst + 57344 + off);
        const bf16x8 bw = *(const bf16x8*)(wp + i * 16);
        acc = mfma32(bw, bh, acc);
        acc = mfma32(bw, bl, acc);
      }
#pragma unroll
      for (int r = 0; r < 16; ++r) {
        const int rowD = (r & 3) + 8 * (r >> 2) + 4 * lhi;
        gh2f[(kh * 96 + s2 * 32 + rowD) * 32 + (l31 ^ rowD)] = acc[r];
      }
    }
    __syncthreads();

    // ---- P3: elementwise GRU cell (merge 2 slots) + swizzled h stores + ornn ----
    if (tid < 512) {
      const int b0 = (0 * 32 + ec) * 32, b1 = (1 * 32 + ec) * 32, b2 = (2 * 32 + ec) * 32;
      const int c0 = eb ^ ec, c1 = eb ^ (ec + 1);
      const float ghr0 = gh2f[b0 + c0] + gh2f[3072 + b0 + c0] + bh0;
      const float ghr1 = gh2f[b0 + 32 + c1] + gh2f[3072 + b0 + 32 + c1] + bh1;
      const float ghz0 = gh2f[b1 + c0] + gh2f[3072 + b1 + c0] + bh2;
      const float ghz1 = gh2f[b1 + 32 + c1] + gh2f[3072 + b1 + 32 + c1] + bh3;
      const float ghn0 = gh2f[b2 + c0] + gh2f[3072 + b2 + c0] + bh4;
      const float ghn1 = gh2f[b2 + 32 + c1] + gh2f[3072 + b2 + 32 + c1] + bh5;
      const float r0 = 1.f / (1.f + __expf(-(pxr.x + ghr0)));
      const float r1 = 1.f / (1.f + __expf(-(pxr.y + ghr1)));
      const float z0 = 1.f / (1.f + __expf(-(pxz.x + ghz0)));
      const float z1 = 1.f / (1.f + __expf(-(pxz.y + ghz1)));
      const float e0 = __expf(2.f * (pxn.x + r0 * ghn0));
      const float e1 = __expf(2.f * (pxn.y + r1 * ghn1));
      const float n0 = 1.f - 2.f / (e0 + 1.f);
      const float n1 = 1.f - 2.f / (e1 + 1.f);
      hown0 = (1.f - z0) * n0 + z0 * hown0;
      hown1 = (1.f - z1) * n1 + z1 * hown1;
      const unsigned short h0 = f2bf(hown0), h1 = f2bf(hown1);
      const unsigned short l0 = f2bf(hown0 - bf2f(h0)), l1 = f2bf(hown1 - bf2f(h1));
      const unsigned hi01 = (unsigned)h0 | ((unsigned)h1 << 16);
      const unsigned lo01 = (unsigned)l0 | ((unsigned)l1 << 16);
      char* hb = (char*)hbuf + wb * 114688;
      const int off = hswz(eb, 2 * (j0 + ec));
      astore32((unsigned*)(hb + off), hi01);
      astore32((unsigned*)(hb + off + 57344), lo01);
      *(unsigned*)(ornn + ((size_t)tl * 32 + eb) * H_ + j0 + ec) = hi01;
    }

    // ---- P4: drain, arrive, lane-parallel poll ----
    asm volatile("s_waitcnt vmcnt(0)" ::: "memory");
    __syncthreads();
    const unsigned tgt = (unsigned)(t + 1);
    if (tid == 0) astore32(arr + blockIdx.x, tgt);
    if (wid == 0) {
      for (;;) {
        const unsigned v = (lane < NWG_SCAN) ? aload32(arr + lane) : tgt;
        if (__all(v >= tgt)) break;
        __builtin_amdgcn_s_sleep(1);
      }
    }
    __syncthreads();
  }
}

extern "C" void kernel_launch(void* const* d_in, const int* in_sizes, int n_in,
                              void* d_out, int out_size, void* d_ws, size_t ws_size,
                              hipStream_t stream) {
  (void)in_sizes; (void)n_in; (void)out_size;
  const int* sample = (const int*)d_in[0];
  const float* icnd = (const float*)d_in[1];
  const float* emb = (const float*)d_in[2];
  const float* wih = (const float*)d_in[3];
  const float* whh = (const float*)d_in[4];
  const float* bih = (const float*)d_in[5];
  const float* bhh = (const float*)d_in[6];
  const float* fc1w = (const float*)d_in[7];
  const float* fc1b = (const float*)d_in[8];
  const float* fc2w = (const float*)d_in[9];
  const float* fc2b = (const float*)d_in[10];
  float* out = (float*)d_out;
  char* ws = (char*)d_ws;

  size_t off = 0;
  auto alloc = [&](size_t bytes) {
    size_t o = off;
    off = (off + bytes + 255) & ~(size_t)255;
    return o;
  };
  const size_t o_arr = alloc(256);
  const size_t o_h = alloc((size_t)2 * 114688);  // swizzled h, 2 time slots
  const size_t zero_end = off;
  const size_t o_emb = alloc((size_t)O_ * EMB_ * 2);
  const size_t o_wih = alloc((size_t)G3_ * XD_ * 2);
  const size_t o_whh = alloc((size_t)G3_ * H_ * 2);
  const size_t o_f1w = alloc((size_t)H_ * H_ * 2);
  const size_t o_f2w = alloc((size_t)O_ * H_ * 2);
  const size_t head = off;

  int Tc = 512;
  while (Tc > 8) {
    size_t need = head + (size_t)Tc * 32 * G3_ * 4 + 2 * ((size_t)Tc * 32 * H_ * 2) + 4096;
    if (need <= ws_size) break;
    Tc >>= 1;
  }
  const size_t o_gat = alloc((size_t)Tc * 32 * G3_ * 4);
  const size_t o_orn = alloc((size_t)Tc * 32 * H_ * 2);
  const size_t o_hid = alloc((size_t)Tc * 32 * H_ * 2);
  (void)o_gat; (void)o_orn; (void)o_hid;

  unsigned short* embb = (unsigned short*)(ws + o_emb);
  unsigned short* wihb = (unsigned short*)(ws + o_wih);
  unsigned short* whhb = (unsigned short*)(ws + o_whh);
  unsigned short* f1wb = (unsigned short*)(ws + o_f1w);
  unsigned short* f2wb = (unsigned short*)(ws + o_f2w);
  float* gat = (float*)(ws + o_gat);
  unsigned short* orn = (unsigned short*)(ws + o_orn);
  unsigned short* hid = (unsigned short*)(ws + o_hid);
  unsigned long long* hbuf = (unsigned long long*)(ws + o_h);
  unsigned int* arr = (unsigned int*)(ws + o_arr);

  // zero arrival slots + h state (required every call: deterministic replays)
  (void)hipMemsetAsync(ws, 0, zero_end, stream);

  cvt_bf16<<<512, 256, 0, stream>>>(emb, embb, O_ * EMB_);
  cvt_bf16<<<1024, 256, 0, stream>>>(wih, wihb, G3_ * XD_);
  cvt_bf16<<<1024, 256, 0, stream>>>(whh, whhb, G3_ * H_);
  cvt_bf16<<<512, 256, 0, stream>>>(fc1w, f1wb, H_ * H_);
  cvt_bf16<<<512, 256, 0, stream>>>(fc2w, f2wb, O_ * H_);

  const int nch = T_FULL / Tc;
  const int M = Tc * 32;
  for (int c = 0; c < nch; ++c) {
    const int t0 = c * Tc;
    gemm_bf16<0><<<dim3(G3_ / 128, M / 128), 256, 0, stream>>>(
        nullptr, sample, icnd, embb, wihb, bih, gat, nullptr, t0);
    scan_gru<<<NWG_SCAN, THR_SCAN, 0, stream>>>(gat, whhb, bhh, hbuf, orn, arr, t0, Tc);
    gemm_bf16<1><<<dim3(H_ / 128, M / 128), 256, 0, stream>>>(
        orn, nullptr, nullptr, nullptr, f1wb, fc1b, nullptr, hid, t0);
    gemm_bf16<2><<<dim3(O_ / 128, M / 128), 256, 0, stream>>>(
        hid, nullptr, nullptr, nullptr, f2wb, fc2b, out, nullptr, t0);
  }
}